// Round 6
// baseline (334.426 us; speedup 1.0000x reference)
//
#include <hip/hip_runtime.h>
#include <hip/hip_bf16.h>
#include <stdint.h>

// Re-Attention: x@Wqkv -> qk^T softmax -> cross-head mix -> LN(head axis) -> @v -> proj
// B=8 N=1024 H=8 D=64 DIM=512
// Round 6: round-5 structure with the cross-wave reduction bug fixed: each wave's
// partial O (over its 256-wide j-strip) goes to its own LDS region; one barrier;
// all threads sum the 4 partials and store. Main loop remains barrier-free.

#define DIMC 512

typedef __attribute__((ext_vector_type(8))) short bf16x8;
typedef __attribute__((ext_vector_type(4))) float f32x4;
typedef __attribute__((ext_vector_type(8))) unsigned short u16x8;

__device__ __forceinline__ unsigned short f2bf(float f) {
    union { float f; uint32_t u; } v; v.f = f;
    uint32_t u = v.u;
    return (unsigned short)((u + 0x7fffu + ((u >> 16) & 1u)) >> 16);
}
__device__ __forceinline__ float bf2f(unsigned short s) {
    union { uint32_t u; float f; } v; v.u = ((uint32_t)s) << 16;
    return v.f;
}

#define MFMA(a, b, c) __builtin_amdgcn_mfma_f32_16x16x32_bf16((a), (b), (c), 0, 0, 0)

#define GLOAD16(gptr, lptr)                                                        \
    __builtin_amdgcn_global_load_lds((const __attribute__((address_space(1))) void*)(gptr), \
                                     (__attribute__((address_space(3))) void*)(lptr), 16, 0, 0)

// ---------- fp32 -> bf16 bulk convert (8 elems/thread) ----------
__global__ void k_conv(const float* __restrict__ in, unsigned short* __restrict__ out, int n8) {
    int t = blockIdx.x * blockDim.x + threadIdx.x;
    if (t >= n8) return;
    const float4* p = reinterpret_cast<const float4*>(in) + (size_t)t * 2;
    float4 a = p[0], b = p[1];
    u16x8 o;
    o[0] = f2bf(a.x); o[1] = f2bf(a.y); o[2] = f2bf(a.z); o[3] = f2bf(a.w);
    o[4] = f2bf(b.x); o[5] = f2bf(b.y); o[6] = f2bf(b.z); o[7] = f2bf(b.w);
    *(reinterpret_cast<u16x8*>(out) + t) = o;
}

// ---------- fp32 [R][C] -> bf16 [C][R] transpose-convert ----------
__global__ __launch_bounds__(256) void k_tconv(const float* __restrict__ in,
                                               unsigned short* __restrict__ out, int R, int C) {
    __shared__ float tile[64][65];
    int ct = C >> 6;
    int bx = blockIdx.x % ct;
    int by = blockIdx.x / ct;
    int r0 = by * 64, c0 = bx * 64;
    int tx = threadIdx.x & 63, ty = threadIdx.x >> 6;
#pragma unroll
    for (int rr = 0; rr < 16; rr++) {
        int row = ty + rr * 4;
        tile[row][tx] = in[(size_t)(r0 + row) * C + c0 + tx];
    }
    __syncthreads();
#pragma unroll
    for (int rr = 0; rr < 16; rr++) {
        int row = ty + rr * 4;
        out[(size_t)(c0 + row) * R + r0 + tx] = f2bf(tile[tx][row]);
    }
}

// ---------- QKV GEMM, 128x128 LDS tile: xb[8192][512] @ wbT^T -> q(scaled)/k/v ----------
__global__ __launch_bounds__(256) void k_qkv(const unsigned short* __restrict__ A,
                                             const unsigned short* __restrict__ BT,
                                             unsigned short* __restrict__ q,
                                             unsigned short* __restrict__ kk,
                                             unsigned short* __restrict__ vv) {
    __shared__ unsigned short Al[128 * 32];
    __shared__ unsigned short Bl[128 * 32];
    int mt = blockIdx.x / 12, nt = blockIdx.x % 12;
    int m0 = mt * 128, c0 = nt * 128;
    int tid = threadIdx.x, lane = tid & 63, w = tid >> 6;
    int wr = w >> 1, wc = w & 1;
    int lr = lane & 15, lb = lane >> 4;
    f32x4 acc[4][4] = {};
    const unsigned short* gA = A + (size_t)(m0 + 32 * w + (lane >> 2)) * DIMC + (lane & 3) * 8;
    const unsigned short* gB = BT + (size_t)(c0 + 32 * w + (lane >> 2)) * DIMC + (lane & 3) * 8;
    char* lA = (char*)Al + w * 2048;
    char* lB = (char*)Bl + w * 2048;
    for (int k0 = 0; k0 < DIMC; k0 += 32) {
        __syncthreads();
        GLOAD16(gA + k0, lA);
        GLOAD16(gA + k0 + 16 * DIMC, lA + 1024);
        GLOAD16(gB + k0, lB);
        GLOAD16(gB + k0 + 16 * DIMC, lB + 1024);
        __syncthreads();
        bf16x8 af[4], bfr[4];
#pragma unroll
        for (int mi = 0; mi < 4; mi++)
            af[mi] = *reinterpret_cast<const bf16x8*>(&Al[(64 * wr + 16 * mi + lr) * 32 + 8 * lb]);
#pragma unroll
        for (int ni = 0; ni < 4; ni++)
            bfr[ni] = *reinterpret_cast<const bf16x8*>(&Bl[(64 * wc + 16 * ni + lr) * 32 + 8 * lb]);
#pragma unroll
        for (int mi = 0; mi < 4; mi++)
#pragma unroll
            for (int ni = 0; ni < 4; ni++)
                acc[mi][ni] = MFMA(af[mi], bfr[ni], acc[mi][ni]);
    }
#pragma unroll
    for (int ni = 0; ni < 4; ni++) {
        int c = c0 + 64 * wc + 16 * ni + lr;
        int which = c >> 9, rem = c & 511, h = rem >> 6, d = rem & 63;
        unsigned short* dst = which == 0 ? q : (which == 1 ? kk : vv);
        float sc = which == 0 ? 0.125f : 1.0f;  // q pre-scaled by D^-0.5
#pragma unroll
        for (int mi = 0; mi < 4; mi++) {
#pragma unroll
            for (int r = 0; r < 4; r++) {
                int m = m0 + 64 * wr + 16 * mi + 4 * lb + r;
                int b = m >> 10, n = m & 1023;
                dst[(((size_t)(b * 8 + h) * 1024) + n) * 64 + d] = f2bf(acc[mi][ni][r] * sc);
            }
        }
    }
}

// ---------- v [bh][n][d] -> vT [bh][d][n] ----------
__global__ __launch_bounds__(256) void k_vtrans(const unsigned short* __restrict__ v,
                                                unsigned short* __restrict__ vT) {
    __shared__ unsigned short tile[64][72];
    int bh = blockIdx.x >> 4;
    int n0 = (blockIdx.x & 15) * 64;
    int t = threadIdx.x;
    int nl = t >> 2, c4 = t & 3;
    const u16x8* src = reinterpret_cast<const u16x8*>(v + ((size_t)bh * 1024 + n0 + nl) * 64 + c4 * 16);
    u16x8 x0 = src[0], x1 = src[1];
    *reinterpret_cast<u16x8*>(&tile[nl][c4 * 16]) = x0;
    *reinterpret_cast<u16x8*>(&tile[nl][c4 * 16 + 8]) = x1;
    __syncthreads();
    int dl = t >> 2, n4 = t & 3;
#pragma unroll
    for (int c = 0; c < 2; c++) {
        u16x8 o;
#pragma unroll
        for (int i = 0; i < 8; i++) o[i] = tile[n4 * 16 + 8 * c + i][dl];
        *reinterpret_cast<u16x8*>(vT + ((size_t)bh * 64 + dl) * 1024 + n0 + n4 * 16 + 8 * c) = o;
    }
}

// ---------- QK^T + full-row softmax -> P bf16 [bh][i][j] ----------
// block = (bh, 16 i-rows); grid 4096; 8 waves each own a 128-wide j strip.
// P stores repacked through per-wave LDS tile for 16B coalesced writes.
__global__ __launch_bounds__(512) void k_attn(const unsigned short* __restrict__ q,
                                              const unsigned short* __restrict__ kk,
                                              unsigned short* __restrict__ P) {
    __shared__ float redm[16][8];
    __shared__ float redl[16][8];
    __shared__ unsigned short stg[8][16 * 136];   // per-wave [16][136] (272B row stride)
    int blk = blockIdx.x;
    int bh = blk & 63, it = blk >> 6;
    int i0 = it * 16;
    int tid = threadIdx.x, w = tid >> 6, lane = tid & 63;
    int lr = lane & 15, lb = lane >> 4;
    int j0 = w * 128;
    const unsigned short* qp = q + (size_t)bh * 65536;
    const unsigned short* kp = kk + (size_t)bh * 65536;
    bf16x8 aq[2];
#pragma unroll
    for (int ks = 0; ks < 2; ks++)
        aq[ks] = *reinterpret_cast<const bf16x8*>(qp + (size_t)(i0 + lr) * 64 + 32 * ks + 8 * lb);
    f32x4 acc[8] = {};
#pragma unroll
    for (int nf = 0; nf < 8; nf++) {
#pragma unroll
        for (int ks = 0; ks < 2; ks++) {
            bf16x8 bk = *reinterpret_cast<const bf16x8*>(kp + (size_t)(j0 + 16 * nf + lr) * 64 + 32 * ks + 8 * lb);
            acc[nf] = MFMA(aq[ks], bk, acc[nf]);
        }
    }
    float mx[4], li[4];
#pragma unroll
    for (int r = 0; r < 4; r++) {
        float m = acc[0][r];
#pragma unroll
        for (int nf = 1; nf < 8; nf++) m = fmaxf(m, acc[nf][r]);
        m = fmaxf(m, __shfl_xor(m, 1)); m = fmaxf(m, __shfl_xor(m, 2));
        m = fmaxf(m, __shfl_xor(m, 4)); m = fmaxf(m, __shfl_xor(m, 8));
        mx[r] = m;
    }
    if (lr == 0) {
#pragma unroll
        for (int r = 0; r < 4; r++) redm[4 * lb + r][w] = mx[r];
    }
    __syncthreads();
#pragma unroll
    for (int r = 0; r < 4; r++) {
        float m = redm[4 * lb + r][0];
#pragma unroll
        for (int ww = 1; ww < 8; ww++) m = fmaxf(m, redm[4 * lb + r][ww]);
        mx[r] = m;
    }
#pragma unroll
    for (int r = 0; r < 4; r++) {
        float s = 0.f;
#pragma unroll
        for (int nf = 0; nf < 8; nf++) {
            float e = __expf(acc[nf][r] - mx[r]);
            acc[nf][r] = e;
            s += e;
        }
        s += __shfl_xor(s, 1); s += __shfl_xor(s, 2);
        s += __shfl_xor(s, 4); s += __shfl_xor(s, 8);
        li[r] = s;
    }
    if (lr == 0) {
#pragma unroll
        for (int r = 0; r < 4; r++) redl[4 * lb + r][w] = li[r];
    }
    __syncthreads();
#pragma unroll
    for (int r = 0; r < 4; r++) {
        float s = 0.f;
#pragma unroll
        for (int ww = 0; ww < 8; ww++) s += redl[4 * lb + r][ww];
        li[r] = 1.0f / s;
    }
    // stage normalized P into per-wave LDS tile, then coalesced 16B stores
    unsigned short* sp = &stg[w][0];
#pragma unroll
    for (int nf = 0; nf < 8; nf++)
#pragma unroll
        for (int r = 0; r < 4; r++)
            sp[(4 * lb + r) * 136 + 16 * nf + lr] = f2bf(acc[nf][r] * li[r]);
    unsigned short* pp = P + (size_t)bh * 1048576;
#pragma unroll
    for (int ss = 0; ss < 4; ss++) {
        int rowi = 4 * ss + lb;
        u16x8 vv = *reinterpret_cast<const u16x8*>(&stg[w][rowi * 136 + lr * 8]);
        *reinterpret_cast<u16x8*>(pp + (size_t)(i0 + rowi) * 1024 + j0 + lr * 8) = vv;
    }
}

// ---------- mix + LN + PV fused, barrier-free main loop ----------
// block = (b, 16 i-rows); grid 512; 4 waves, wave w owns j in [w*256,(w+1)*256).
// Lane l handles i = i0+(l&15), j-chunk elems 8*(l>>4)+0..7 per 32-j chunk:
// loads all 8 heads' P directly (16B/head), mixes+LNs in-register; outputs are
// exactly MFMA B-fragments (swapped PV: O^T = vT * PM^T). accO = partial O over
// the wave's j-strip; partials land in per-wave LDS regions, summed after one
// barrier by all threads (fixes round-5 race).
__global__ __launch_bounds__(256, 2) void k_mixpv(const unsigned short* __restrict__ P,
                                                  const unsigned short* __restrict__ vT,
                                                  const float* __restrict__ Wm,
                                                  const float* __restrict__ gamma,
                                                  const float* __restrict__ beta,
                                                  unsigned short* __restrict__ outh) {
    __shared__ unsigned short Op[4][16 * 512];   // per-wave bf16 partials, 64 KB total
    int blk = blockIdx.x;
    int b = blk & 7, it = blk >> 3;
    int i0 = it * 16;
    int tid = threadIdx.x, w = tid >> 6, lane = tid & 63;
    int li = lane & 15, hi = lane >> 4;
    float wv[64];
#pragma unroll
    for (int x2 = 0; x2 < 64; x2++) wv[x2] = Wm[x2];
    float cv[8];  // mean folding: c_h = sum_g W[h][g] / 8
#pragma unroll
    for (int h = 0; h < 8; h++) {
        float s = 0.f;
#pragma unroll
        for (int g = 0; g < 8; g++) s += wv[h * 8 + g];
        cv[h] = s * 0.125f;
    }
    float gv[8], bvv[8];
#pragma unroll
    for (int x2 = 0; x2 < 8; x2++) { gv[x2] = gamma[x2]; bvv[x2] = beta[x2]; }
    const unsigned short* pb = P + (size_t)b * 8388608 + (size_t)(i0 + li) * 1024 + 8 * hi + w * 256;
    const unsigned short* vb = vT + (size_t)b * 524288 + (size_t)li * 1024 + 8 * hi + w * 256;
    f32x4 accO[8][4] = {};
    u16x8 avh[8];
#pragma unroll
    for (int h = 0; h < 8; h++)
        avh[h] = *reinterpret_cast<const u16x8*>(pb + (size_t)h * 1048576);
#pragma unroll 1
    for (int c = 0; c < 8; c++) {
        int j0c = c * 32;
        u16x8 nxt[8];
        if (c < 7) {
#pragma unroll
            for (int h = 0; h < 8; h++)
                nxt[h] = *reinterpret_cast<const u16x8*>(pb + (size_t)h * 1048576 + j0c + 32);
        }
        // mix + LN for 8 j-entries; results land as B-fragments per head g
        u16x8 bfrag[8];
#pragma unroll
        for (int jj = 0; jj < 8; jj++) {
            float a[8];
#pragma unroll
            for (int h = 0; h < 8; h++) a[h] = bf2f(avh[h][jj]);
            float mg[8];
#pragma unroll
            for (int g = 0; g < 8; g++) {
                float s = 0.f;
#pragma unroll
                for (int h = 0; h < 8; h++) s += a[h] * wv[h * 8 + g];
                mg[g] = s;
            }
            float mean = 0.f;
#pragma unroll
            for (int h = 0; h < 8; h++) mean += a[h] * cv[h];
            float vvar = 0.f;
#pragma unroll
            for (int g = 0; g < 8; g++) { float d = mg[g] - mean; vvar += d * d; }
            float rs = rsqrtf(vvar * 0.125f + 1e-5f);
#pragma unroll
            for (int g = 0; g < 8; g++)
                bfrag[g][jj] = f2bf((mg[g] - mean) * rs * gv[g] + bvv[g]);
        }
        // PV: O^T[d][i] += V^T[d][j] * PM^T[j][i] per head
#pragma unroll
        for (int g = 0; g < 8; g++) {
            const unsigned short* vg = vb + (size_t)g * 65536 + j0c;
            bf16x8 bf = *reinterpret_cast<const bf16x8*>(&bfrag[g]);
#pragma unroll
            for (int df = 0; df < 4; df++) {
                bf16x8 af = *reinterpret_cast<const bf16x8*>(vg + (size_t)df * 16384);
                accO[g][df] = MFMA(af, bf, accO[g][df]);
            }
        }
        if (c < 7) {
#pragma unroll
            for (int h = 0; h < 8; h++) avh[h] = nxt[h];
        }
    }
    // write this wave's partial O (accO[g][df][r] = O[i0+li][g*64+16df+4hi+r]) to its region
#pragma unroll
    for (int g = 0; g < 8; g++)
#pragma unroll
        for (int df = 0; df < 4; df++)
#pragma unroll
            for (int r = 0; r < 4; r++) {
                int idx = li * 512 + g * 64 + df * 16 + hi * 4 + r;
                int byteoff = (idx * 2) ^ ((li & 7) << 5);
                *reinterpret_cast<unsigned short*>((char*)Op[w] + byteoff) = f2bf(accO[g][df][r]);
            }
    __syncthreads();
    // all threads: sum the 4 partials chunk-wise, store coalesced.
    // 1024 chunks of 16B; per s, row is wave-uniform -> swizzle uniform -> linear reads.
#pragma unroll
    for (int s = 0; s < 4; s++) {
        int kch = tid + s * 256;
        int row = kch >> 6, col = (kch & 63) * 8;
        int byteoff = ((row * 512 + col) * 2) ^ ((row & 7) << 5);
        float sum[8] = {};
#pragma unroll
        for (int pw = 0; pw < 4; pw++) {
            u16x8 pv = *reinterpret_cast<const u16x8*>((const char*)Op[pw] + byteoff);
#pragma unroll
            for (int e2 = 0; e2 < 8; e2++) sum[e2] += bf2f(pv[e2]);
        }
        u16x8 ov;
#pragma unroll
        for (int e2 = 0; e2 < 8; e2++) ov[e2] = f2bf(sum[e2]);
        *reinterpret_cast<u16x8*>(outh + (size_t)(b * 1024 + i0 + row) * 512 + col) = ov;
    }
}

// ---------- out = outh @ w_out + b_out (fp32 out), 128x128 LDS tile ----------
__global__ __launch_bounds__(256) void k_proj(const unsigned short* __restrict__ A,
                                              const unsigned short* __restrict__ BT,
                                              const float* __restrict__ bias,
                                              float* __restrict__ out) {
    __shared__ unsigned short Al[128 * 32];
    __shared__ unsigned short Bl[128 * 32];
    int mt = blockIdx.x >> 2, nt = blockIdx.x & 3;
    int m0 = mt * 128, c0 = nt * 128;
    int tid = threadIdx.x, lane = tid & 63, w = tid >> 6;
    int wr = w >> 1, wc = w & 1;
    int lr = lane & 15, lb = lane >> 4;
    f32x4 acc[4][4] = {};
    const unsigned short* gA = A + (size_t)(m0 + 32 * w + (lane >> 2)) * DIMC + (lane & 3) * 8;
    const unsigned short* gB = BT + (size_t)(c0 + 32 * w + (lane >> 2)) * DIMC + (lane & 3) * 8;
    char* lA = (char*)Al + w * 2048;
    char* lB = (char*)Bl + w * 2048;
    for (int k0 = 0; k0 < DIMC; k0 += 32) {
        __syncthreads();
        GLOAD16(gA + k0, lA);
        GLOAD16(gA + k0 + 16 * DIMC, lA + 1024);
        GLOAD16(gB + k0, lB);
        GLOAD16(gB + k0 + 16 * DIMC, lB + 1024);
        __syncthreads();
        bf16x8 af[4], bfr[4];
#pragma unroll
        for (int mi = 0; mi < 4; mi++)
            af[mi] = *reinterpret_cast<const bf16x8*>(&Al[(64 * wr + 16 * mi + lr) * 32 + 8 * lb]);
#pragma unroll
        for (int ni = 0; ni < 4; ni++)
            bfr[ni] = *reinterpret_cast<const bf16x8*>(&Bl[(64 * wc + 16 * ni + lr) * 32 + 8 * lb]);
#pragma unroll
        for (int mi = 0; mi < 4; mi++)
#pragma unroll
            for (int ni = 0; ni < 4; ni++)
                acc[mi][ni] = MFMA(af[mi], bfr[ni], acc[mi][ni]);
    }
#pragma unroll
    for (int ni = 0; ni < 4; ni++) {
        int c = c0 + 64 * wc + 16 * ni + lr;
        float bs = bias[c];
#pragma unroll
        for (int mi = 0; mi < 4; mi++) {
#pragma unroll
            for (int r = 0; r < 4; r++) {
                int m = m0 + 64 * wr + 16 * mi + 4 * lb + r;
                out[(size_t)m * 512 + c] = acc[mi][ni][r] + bs;
            }
        }
    }
}

extern "C" void kernel_launch(void* const* d_in, const int* in_sizes, int n_in,
                              void* d_out, int out_size, void* d_ws, size_t ws_size,
                              hipStream_t stream) {
    (void)in_sizes; (void)n_in; (void)out_size; (void)ws_size;
    const float* x      = (const float*)d_in[0];
    const float* w_qkv  = (const float*)d_in[1];
    const float* W      = (const float*)d_in[2];
    const float* gamma  = (const float*)d_in[3];
    const float* beta   = (const float*)d_in[4];
    const float* w_out  = (const float*)d_in[5];
    const float* b_out  = (const float*)d_in[6];
    float* out = (float*)d_out;

    char* ws = (char*)d_ws;
    unsigned short* xb   = (unsigned short*)(ws + 0);           //  8 MB  [8192][512]
    unsigned short* wbT  = (unsigned short*)(ws + 8388608);     //  1.5MB [1536][512]
    unsigned short* w_oT = (unsigned short*)(ws + 9961472);     //  0.5MB [512][512]
    unsigned short* q    = (unsigned short*)(ws + 10485760);    //  8 MB  [bh][n][d]
    unsigned short* k    = (unsigned short*)(ws + 18874368);    //  8 MB
    unsigned short* v    = (unsigned short*)(ws + 27262976);    //  8 MB
    unsigned short* vT   = (unsigned short*)(ws + 35651584);    //  8 MB  [bh][d][n]
    unsigned short* outh = (unsigned short*)(ws + 44040192);    //  8 MB  [8192][512]
    unsigned short* P    = (unsigned short*)(ws + 52428800);    // 128 MB [bh][i][j]

    k_conv<<<2048, 256, 0, stream>>>(x, xb, 8192 * 512 / 8);
    k_tconv<<<(512 / 64) * (1536 / 64), 256, 0, stream>>>(w_qkv, wbT, 512, 1536);
    k_tconv<<<(512 / 64) * (512 / 64), 256, 0, stream>>>(w_out, w_oT, 512, 512);
    k_qkv<<<(8192 / 128) * (1536 / 128), 256, 0, stream>>>(xb, wbT, q, k, v);
    k_vtrans<<<64 * 16, 256, 0, stream>>>(v, vT);
    k_attn<<<64 * 64, 512, 0, stream>>>(q, k, P);
    k_mixpv<<<8 * 64, 256, 0, stream>>>(P, vT, W, gamma, beta, outh);
    k_proj<<<(8192 / 128) * (512 / 128), 256, 0, stream>>>(outh, w_oT, b_out, out);
}

// Round 7
// 304.569 us; speedup vs baseline: 1.0980x; 1.0980x over previous
//
#include <hip/hip_runtime.h>
#include <hip/hip_bf16.h>
#include <stdint.h>

// Re-Attention: x@Wqkv -> qk^T softmax -> cross-head mix -> LN(head axis) -> @v -> proj
// B=8 N=1024 H=8 D=64 DIM=512
// Round 7: k_mixpv spill fix — removed nxt[8] manual prefetch (was pushing regs
// past 256/wave -> 160MB scratch writes); packed partial-O stores as 8B writes.
// Main loop stays barrier-free; per-wave partials summed after one barrier.

#define DIMC 512

typedef __attribute__((ext_vector_type(8))) short bf16x8;
typedef __attribute__((ext_vector_type(4))) float f32x4;
typedef __attribute__((ext_vector_type(8))) unsigned short u16x8;
typedef __attribute__((ext_vector_type(4))) unsigned short u16x4;

__device__ __forceinline__ unsigned short f2bf(float f) {
    union { float f; uint32_t u; } v; v.f = f;
    uint32_t u = v.u;
    return (unsigned short)((u + 0x7fffu + ((u >> 16) & 1u)) >> 16);
}
__device__ __forceinline__ float bf2f(unsigned short s) {
    union { uint32_t u; float f; } v; v.u = ((uint32_t)s) << 16;
    return v.f;
}

#define MFMA(a, b, c) __builtin_amdgcn_mfma_f32_16x16x32_bf16((a), (b), (c), 0, 0, 0)

#define GLOAD16(gptr, lptr)                                                        \
    __builtin_amdgcn_global_load_lds((const __attribute__((address_space(1))) void*)(gptr), \
                                     (__attribute__((address_space(3))) void*)(lptr), 16, 0, 0)

// ---------- fp32 -> bf16 bulk convert (8 elems/thread) ----------
__global__ void k_conv(const float* __restrict__ in, unsigned short* __restrict__ out, int n8) {
    int t = blockIdx.x * blockDim.x + threadIdx.x;
    if (t >= n8) return;
    const float4* p = reinterpret_cast<const float4*>(in) + (size_t)t * 2;
    float4 a = p[0], b = p[1];
    u16x8 o;
    o[0] = f2bf(a.x); o[1] = f2bf(a.y); o[2] = f2bf(a.z); o[3] = f2bf(a.w);
    o[4] = f2bf(b.x); o[5] = f2bf(b.y); o[6] = f2bf(b.z); o[7] = f2bf(b.w);
    *(reinterpret_cast<u16x8*>(out) + t) = o;
}

// ---------- fp32 [R][C] -> bf16 [C][R] transpose-convert ----------
__global__ __launch_bounds__(256) void k_tconv(const float* __restrict__ in,
                                               unsigned short* __restrict__ out, int R, int C) {
    __shared__ float tile[64][65];
    int ct = C >> 6;
    int bx = blockIdx.x % ct;
    int by = blockIdx.x / ct;
    int r0 = by * 64, c0 = bx * 64;
    int tx = threadIdx.x & 63, ty = threadIdx.x >> 6;
#pragma unroll
    for (int rr = 0; rr < 16; rr++) {
        int row = ty + rr * 4;
        tile[row][tx] = in[(size_t)(r0 + row) * C + c0 + tx];
    }
    __syncthreads();
#pragma unroll
    for (int rr = 0; rr < 16; rr++) {
        int row = ty + rr * 4;
        out[(size_t)(c0 + row) * R + r0 + tx] = f2bf(tile[tx][row]);
    }
}

// ---------- QKV GEMM, 128x128 LDS tile: xb[8192][512] @ wbT^T -> q(scaled)/k/v ----------
__global__ __launch_bounds__(256) void k_qkv(const unsigned short* __restrict__ A,
                                             const unsigned short* __restrict__ BT,
                                             unsigned short* __restrict__ q,
                                             unsigned short* __restrict__ kk,
                                             unsigned short* __restrict__ vv) {
    __shared__ unsigned short Al[128 * 32];
    __shared__ unsigned short Bl[128 * 32];
    int mt = blockIdx.x / 12, nt = blockIdx.x % 12;
    int m0 = mt * 128, c0 = nt * 128;
    int tid = threadIdx.x, lane = tid & 63, w = tid >> 6;
    int wr = w >> 1, wc = w & 1;
    int lr = lane & 15, lb = lane >> 4;
    f32x4 acc[4][4] = {};
    const unsigned short* gA = A + (size_t)(m0 + 32 * w + (lane >> 2)) * DIMC + (lane & 3) * 8;
    const unsigned short* gB = BT + (size_t)(c0 + 32 * w + (lane >> 2)) * DIMC + (lane & 3) * 8;
    char* lA = (char*)Al + w * 2048;
    char* lB = (char*)Bl + w * 2048;
    for (int k0 = 0; k0 < DIMC; k0 += 32) {
        __syncthreads();
        GLOAD16(gA + k0, lA);
        GLOAD16(gA + k0 + 16 * DIMC, lA + 1024);
        GLOAD16(gB + k0, lB);
        GLOAD16(gB + k0 + 16 * DIMC, lB + 1024);
        __syncthreads();
        bf16x8 af[4], bfr[4];
#pragma unroll
        for (int mi = 0; mi < 4; mi++)
            af[mi] = *reinterpret_cast<const bf16x8*>(&Al[(64 * wr + 16 * mi + lr) * 32 + 8 * lb]);
#pragma unroll
        for (int ni = 0; ni < 4; ni++)
            bfr[ni] = *reinterpret_cast<const bf16x8*>(&Bl[(64 * wc + 16 * ni + lr) * 32 + 8 * lb]);
#pragma unroll
        for (int mi = 0; mi < 4; mi++)
#pragma unroll
            for (int ni = 0; ni < 4; ni++)
                acc[mi][ni] = MFMA(af[mi], bfr[ni], acc[mi][ni]);
    }
#pragma unroll
    for (int ni = 0; ni < 4; ni++) {
        int c = c0 + 64 * wc + 16 * ni + lr;
        int which = c >> 9, rem = c & 511, h = rem >> 6, d = rem & 63;
        unsigned short* dst = which == 0 ? q : (which == 1 ? kk : vv);
        float sc = which == 0 ? 0.125f : 1.0f;  // q pre-scaled by D^-0.5
#pragma unroll
        for (int mi = 0; mi < 4; mi++) {
#pragma unroll
            for (int r = 0; r < 4; r++) {
                int m = m0 + 64 * wr + 16 * mi + 4 * lb + r;
                int b = m >> 10, n = m & 1023;
                dst[(((size_t)(b * 8 + h) * 1024) + n) * 64 + d] = f2bf(acc[mi][ni][r] * sc);
            }
        }
    }
}

// ---------- v [bh][n][d] -> vT [bh][d][n] ----------
__global__ __launch_bounds__(256) void k_vtrans(const unsigned short* __restrict__ v,
                                                unsigned short* __restrict__ vT) {
    __shared__ unsigned short tile[64][72];
    int bh = blockIdx.x >> 4;
    int n0 = (blockIdx.x & 15) * 64;
    int t = threadIdx.x;
    int nl = t >> 2, c4 = t & 3;
    const u16x8* src = reinterpret_cast<const u16x8*>(v + ((size_t)bh * 1024 + n0 + nl) * 64 + c4 * 16);
    u16x8 x0 = src[0], x1 = src[1];
    *reinterpret_cast<u16x8*>(&tile[nl][c4 * 16]) = x0;
    *reinterpret_cast<u16x8*>(&tile[nl][c4 * 16 + 8]) = x1;
    __syncthreads();
    int dl = t >> 2, n4 = t & 3;
#pragma unroll
    for (int c = 0; c < 2; c++) {
        u16x8 o;
#pragma unroll
        for (int i = 0; i < 8; i++) o[i] = tile[n4 * 16 + 8 * c + i][dl];
        *reinterpret_cast<u16x8*>(vT + ((size_t)bh * 64 + dl) * 1024 + n0 + n4 * 16 + 8 * c) = o;
    }
}

// ---------- QK^T + full-row softmax -> P bf16 [bh][i][j] ----------
// block = (bh, 16 i-rows); grid 4096; 8 waves each own a 128-wide j strip.
// P stores repacked through per-wave LDS tile for 16B coalesced writes.
__global__ __launch_bounds__(512) void k_attn(const unsigned short* __restrict__ q,
                                              const unsigned short* __restrict__ kk,
                                              unsigned short* __restrict__ P) {
    __shared__ float redm[16][8];
    __shared__ float redl[16][8];
    __shared__ unsigned short stg[8][16 * 136];   // per-wave [16][136] (272B row stride)
    int blk = blockIdx.x;
    int bh = blk & 63, it = blk >> 6;
    int i0 = it * 16;
    int tid = threadIdx.x, w = tid >> 6, lane = tid & 63;
    int lr = lane & 15, lb = lane >> 4;
    int j0 = w * 128;
    const unsigned short* qp = q + (size_t)bh * 65536;
    const unsigned short* kp = kk + (size_t)bh * 65536;
    bf16x8 aq[2];
#pragma unroll
    for (int ks = 0; ks < 2; ks++)
        aq[ks] = *reinterpret_cast<const bf16x8*>(qp + (size_t)(i0 + lr) * 64 + 32 * ks + 8 * lb);
    f32x4 acc[8] = {};
#pragma unroll
    for (int nf = 0; nf < 8; nf++) {
#pragma unroll
        for (int ks = 0; ks < 2; ks++) {
            bf16x8 bk = *reinterpret_cast<const bf16x8*>(kp + (size_t)(j0 + 16 * nf + lr) * 64 + 32 * ks + 8 * lb);
            acc[nf] = MFMA(aq[ks], bk, acc[nf]);
        }
    }
    float mx[4], li[4];
#pragma unroll
    for (int r = 0; r < 4; r++) {
        float m = acc[0][r];
#pragma unroll
        for (int nf = 1; nf < 8; nf++) m = fmaxf(m, acc[nf][r]);
        m = fmaxf(m, __shfl_xor(m, 1)); m = fmaxf(m, __shfl_xor(m, 2));
        m = fmaxf(m, __shfl_xor(m, 4)); m = fmaxf(m, __shfl_xor(m, 8));
        mx[r] = m;
    }
    if (lr == 0) {
#pragma unroll
        for (int r = 0; r < 4; r++) redm[4 * lb + r][w] = mx[r];
    }
    __syncthreads();
#pragma unroll
    for (int r = 0; r < 4; r++) {
        float m = redm[4 * lb + r][0];
#pragma unroll
        for (int ww = 1; ww < 8; ww++) m = fmaxf(m, redm[4 * lb + r][ww]);
        mx[r] = m;
    }
#pragma unroll
    for (int r = 0; r < 4; r++) {
        float s = 0.f;
#pragma unroll
        for (int nf = 0; nf < 8; nf++) {
            float e = __expf(acc[nf][r] - mx[r]);
            acc[nf][r] = e;
            s += e;
        }
        s += __shfl_xor(s, 1); s += __shfl_xor(s, 2);
        s += __shfl_xor(s, 4); s += __shfl_xor(s, 8);
        li[r] = s;
    }
    if (lr == 0) {
#pragma unroll
        for (int r = 0; r < 4; r++) redl[4 * lb + r][w] = li[r];
    }
    __syncthreads();
#pragma unroll
    for (int r = 0; r < 4; r++) {
        float s = 0.f;
#pragma unroll
        for (int ww = 0; ww < 8; ww++) s += redl[4 * lb + r][ww];
        li[r] = 1.0f / s;
    }
    // stage normalized P into per-wave LDS tile, then coalesced 16B stores
    unsigned short* sp = &stg[w][0];
#pragma unroll
    for (int nf = 0; nf < 8; nf++)
#pragma unroll
        for (int r = 0; r < 4; r++)
            sp[(4 * lb + r) * 136 + 16 * nf + lr] = f2bf(acc[nf][r] * li[r]);
    unsigned short* pp = P + (size_t)bh * 1048576;
#pragma unroll
    for (int ss = 0; ss < 4; ss++) {
        int rowi = 4 * ss + lb;
        u16x8 vv = *reinterpret_cast<const u16x8*>(&stg[w][rowi * 136 + lr * 8]);
        *reinterpret_cast<u16x8*>(pp + (size_t)(i0 + rowi) * 1024 + j0 + lr * 8) = vv;
    }
}

// ---------- mix + LN + PV fused, barrier-free main loop ----------
// block = (b, 16 i-rows); grid 512; 4 waves, wave w owns j in [w*256,(w+1)*256).
// Lane l handles i = i0+(l&15), j elems 8*(l>>4)+0..7 per 32-j chunk: loads all
// 8 heads' P (16B/head), mixes+LNs in-register; outputs are MFMA B-fragments
// (swapped PV: O^T = vT * PM^T). Per-wave partial O -> own LDS region -> one
// barrier -> all threads sum 4 partials and store. No prefetch (reg budget).
__global__ __launch_bounds__(256, 2) void k_mixpv(const unsigned short* __restrict__ P,
                                                  const unsigned short* __restrict__ vT,
                                                  const float* __restrict__ Wm,
                                                  const float* __restrict__ gamma,
                                                  const float* __restrict__ beta,
                                                  unsigned short* __restrict__ outh) {
    __shared__ unsigned short Op[4][16 * 512];   // per-wave bf16 partials, 64 KB total
    int blk = blockIdx.x;
    int b = blk & 7, it = blk >> 3;
    int i0 = it * 16;
    int tid = threadIdx.x, w = tid >> 6, lane = tid & 63;
    int li = lane & 15, hi = lane >> 4;
    float wv[64];
#pragma unroll
    for (int x2 = 0; x2 < 64; x2++) wv[x2] = Wm[x2];
    float cv[8];  // mean folding: c_h = sum_g W[h][g] / 8
#pragma unroll
    for (int h = 0; h < 8; h++) {
        float s = 0.f;
#pragma unroll
        for (int g = 0; g < 8; g++) s += wv[h * 8 + g];
        cv[h] = s * 0.125f;
    }
    float gv[8], bvv[8];
#pragma unroll
    for (int x2 = 0; x2 < 8; x2++) { gv[x2] = gamma[x2]; bvv[x2] = beta[x2]; }
    const unsigned short* pb = P + (size_t)b * 8388608 + (size_t)(i0 + li) * 1024 + 8 * hi + w * 256;
    const unsigned short* vb = vT + (size_t)b * 524288 + (size_t)li * 1024 + 8 * hi + w * 256;
    f32x4 accO[8][4] = {};
#pragma unroll 1
    for (int c = 0; c < 8; c++) {
        int j0c = c * 32;
        u16x8 avh[8];
#pragma unroll
        for (int h = 0; h < 8; h++)
            avh[h] = *reinterpret_cast<const u16x8*>(pb + (size_t)h * 1048576 + j0c);
        // mix + LN for 8 j-entries; results land as B-fragments per head g
        u16x8 bfrag[8];
#pragma unroll
        for (int jj = 0; jj < 8; jj++) {
            float a[8];
#pragma unroll
            for (int h = 0; h < 8; h++) a[h] = bf2f(avh[h][jj]);
            float mg[8];
#pragma unroll
            for (int g = 0; g < 8; g++) {
                float s = 0.f;
#pragma unroll
                for (int h = 0; h < 8; h++) s += a[h] * wv[h * 8 + g];
                mg[g] = s;
            }
            float mean = 0.f;
#pragma unroll
            for (int h = 0; h < 8; h++) mean += a[h] * cv[h];
            float vvar = 0.f;
#pragma unroll
            for (int g = 0; g < 8; g++) { float d = mg[g] - mean; vvar += d * d; }
            float rs = rsqrtf(vvar * 0.125f + 1e-5f);
#pragma unroll
            for (int g = 0; g < 8; g++)
                bfrag[g][jj] = f2bf((mg[g] - mean) * rs * gv[g] + bvv[g]);
        }
        // PV: O^T[d][i] += V^T[d][j] * PM^T[j][i] per head
#pragma unroll
        for (int g = 0; g < 8; g++) {
            const unsigned short* vg = vb + (size_t)g * 65536 + j0c;
            bf16x8 bf = *reinterpret_cast<const bf16x8*>(&bfrag[g]);
#pragma unroll
            for (int df = 0; df < 4; df++) {
                bf16x8 af = *reinterpret_cast<const bf16x8*>(vg + (size_t)df * 16384);
                accO[g][df] = MFMA(af, bf, accO[g][df]);
            }
        }
    }
    // write this wave's partial O (accO[g][df][r] = O[i0+li][g*64+16df+4hi+r]),
    // packed 4 consecutive u16 -> one 8B store; XOR-swizzled rows
#pragma unroll
    for (int g = 0; g < 8; g++)
#pragma unroll
        for (int df = 0; df < 4; df++) {
            u16x4 pk;
#pragma unroll
            for (int r = 0; r < 4; r++) pk[r] = f2bf(accO[g][df][r]);
            int idx = li * 512 + g * 64 + df * 16 + hi * 4;
            int byteoff = (idx * 2) ^ ((li & 7) << 5);
            *reinterpret_cast<u16x4*>((char*)Op[w] + byteoff) = pk;
        }
    __syncthreads();
    // all threads: sum the 4 partials chunk-wise, store coalesced.
    // 1024 chunks of 16B; per s, row is wave-uniform -> swizzle uniform -> linear reads.
#pragma unroll
    for (int s = 0; s < 4; s++) {
        int kch = tid + s * 256;
        int row = kch >> 6, col = (kch & 63) * 8;
        int byteoff = ((row * 512 + col) * 2) ^ ((row & 7) << 5);
        float sum[8] = {};
#pragma unroll
        for (int pw = 0; pw < 4; pw++) {
            u16x8 pv = *reinterpret_cast<const u16x8*>((const char*)Op[pw] + byteoff);
#pragma unroll
            for (int e2 = 0; e2 < 8; e2++) sum[e2] += bf2f(pv[e2]);
        }
        u16x8 ov;
#pragma unroll
        for (int e2 = 0; e2 < 8; e2++) ov[e2] = f2bf(sum[e2]);
        *reinterpret_cast<u16x8*>(outh + (size_t)(b * 1024 + i0 + row) * 512 + col) = ov;
    }
}

// ---------- out = outh @ w_out + b_out (fp32 out), 128x128 LDS tile ----------
__global__ __launch_bounds__(256) void k_proj(const unsigned short* __restrict__ A,
                                              const unsigned short* __restrict__ BT,
                                              const float* __restrict__ bias,
                                              float* __restrict__ out) {
    __shared__ unsigned short Al[128 * 32];
    __shared__ unsigned short Bl[128 * 32];
    int mt = blockIdx.x >> 2, nt = blockIdx.x & 3;
    int m0 = mt * 128, c0 = nt * 128;
    int tid = threadIdx.x, lane = tid & 63, w = tid >> 6;
    int wr = w >> 1, wc = w & 1;
    int lr = lane & 15, lb = lane >> 4;
    f32x4 acc[4][4] = {};
    const unsigned short* gA = A + (size_t)(m0 + 32 * w + (lane >> 2)) * DIMC + (lane & 3) * 8;
    const unsigned short* gB = BT + (size_t)(c0 + 32 * w + (lane >> 2)) * DIMC + (lane & 3) * 8;
    char* lA = (char*)Al + w * 2048;
    char* lB = (char*)Bl + w * 2048;
    for (int k0 = 0; k0 < DIMC; k0 += 32) {
        __syncthreads();
        GLOAD16(gA + k0, lA);
        GLOAD16(gA + k0 + 16 * DIMC, lA + 1024);
        GLOAD16(gB + k0, lB);
        GLOAD16(gB + k0 + 16 * DIMC, lB + 1024);
        __syncthreads();
        bf16x8 af[4], bfr[4];
#pragma unroll
        for (int mi = 0; mi < 4; mi++)
            af[mi] = *reinterpret_cast<const bf16x8*>(&Al[(64 * wr + 16 * mi + lr) * 32 + 8 * lb]);
#pragma unroll
        for (int ni = 0; ni < 4; ni++)
            bfr[ni] = *reinterpret_cast<const bf16x8*>(&Bl[(64 * wc + 16 * ni + lr) * 32 + 8 * lb]);
#pragma unroll
        for (int mi = 0; mi < 4; mi++)
#pragma unroll
            for (int ni = 0; ni < 4; ni++)
                acc[mi][ni] = MFMA(af[mi], bfr[ni], acc[mi][ni]);
    }
#pragma unroll
    for (int ni = 0; ni < 4; ni++) {
        int c = c0 + 64 * wc + 16 * ni + lr;
        float bs = bias[c];
#pragma unroll
        for (int mi = 0; mi < 4; mi++) {
#pragma unroll
            for (int r = 0; r < 4; r++) {
                int m = m0 + 64 * wr + 16 * mi + 4 * lb + r;
                out[(size_t)m * 512 + c] = acc[mi][ni][r] + bs;
            }
        }
    }
}

extern "C" void kernel_launch(void* const* d_in, const int* in_sizes, int n_in,
                              void* d_out, int out_size, void* d_ws, size_t ws_size,
                              hipStream_t stream) {
    (void)in_sizes; (void)n_in; (void)out_size; (void)ws_size;
    const float* x      = (const float*)d_in[0];
    const float* w_qkv  = (const float*)d_in[1];
    const float* W      = (const float*)d_in[2];
    const float* gamma  = (const float*)d_in[3];
    const float* beta   = (const float*)d_in[4];
    const float* w_out  = (const float*)d_in[5];
    const float* b_out  = (const float*)d_in[6];
    float* out = (float*)d_out;

    char* ws = (char*)d_ws;
    unsigned short* xb   = (unsigned short*)(ws + 0);           //  8 MB  [8192][512]
    unsigned short* wbT  = (unsigned short*)(ws + 8388608);     //  1.5MB [1536][512]
    unsigned short* w_oT = (unsigned short*)(ws + 9961472);     //  0.5MB [512][512]
    unsigned short* q    = (unsigned short*)(ws + 10485760);    //  8 MB  [bh][n][d]
    unsigned short* k    = (unsigned short*)(ws + 18874368);    //  8 MB
    unsigned short* v    = (unsigned short*)(ws + 27262976);    //  8 MB
    unsigned short* vT   = (unsigned short*)(ws + 35651584);    //  8 MB  [bh][d][n]
    unsigned short* outh = (unsigned short*)(ws + 44040192);    //  8 MB  [8192][512]
    unsigned short* P    = (unsigned short*)(ws + 52428800);    // 128 MB [bh][i][j]

    k_conv<<<2048, 256, 0, stream>>>(x, xb, 8192 * 512 / 8);
    k_tconv<<<(512 / 64) * (1536 / 64), 256, 0, stream>>>(w_qkv, wbT, 512, 1536);
    k_tconv<<<(512 / 64) * (512 / 64), 256, 0, stream>>>(w_out, w_oT, 512, 512);
    k_qkv<<<(8192 / 128) * (1536 / 128), 256, 0, stream>>>(xb, wbT, q, k, v);
    k_vtrans<<<64 * 16, 256, 0, stream>>>(v, vT);
    k_attn<<<64 * 64, 512, 0, stream>>>(q, k, P);
    k_mixpv<<<8 * 64, 256, 0, stream>>>(P, vT, W, gamma, beta, outh);
    k_proj<<<(8192 / 128) * (512 / 128), 256, 0, stream>>>(outh, w_oT, b_out, out);
}

// Round 8
// 295.567 us; speedup vs baseline: 1.1315x; 1.0305x over previous
//
#include <hip/hip_runtime.h>
#include <hip/hip_bf16.h>
#include <stdint.h>

// Re-Attention: x@Wqkv -> qk^T softmax -> cross-head mix -> LN(head axis) -> @v -> proj
// B=8 N=1024 H=8 D=64 DIM=512
// Round 8: k_mixpv latency fix — per-wave async double-buffered P staging via
// global_load_lds (zero VGPR cost), explicit vmcnt(0) gating; LDS dbuf reused as
// the partial-O reduction scratch (footprint stays 64 KB, 2 blocks/CU).

#define DIMC 512

typedef __attribute__((ext_vector_type(8))) short bf16x8;
typedef __attribute__((ext_vector_type(4))) float f32x4;
typedef __attribute__((ext_vector_type(8))) unsigned short u16x8;
typedef __attribute__((ext_vector_type(4))) unsigned short u16x4;

__device__ __forceinline__ unsigned short f2bf(float f) {
    union { float f; uint32_t u; } v; v.f = f;
    uint32_t u = v.u;
    return (unsigned short)((u + 0x7fffu + ((u >> 16) & 1u)) >> 16);
}
__device__ __forceinline__ float bf2f(unsigned short s) {
    union { uint32_t u; float f; } v; v.u = ((uint32_t)s) << 16;
    return v.f;
}

#define MFMA(a, b, c) __builtin_amdgcn_mfma_f32_16x16x32_bf16((a), (b), (c), 0, 0, 0)

#define GLOAD16(gptr, lptr)                                                        \
    __builtin_amdgcn_global_load_lds((const __attribute__((address_space(1))) void*)(gptr), \
                                     (__attribute__((address_space(3))) void*)(lptr), 16, 0, 0)

// ---------- fp32 -> bf16 bulk convert (8 elems/thread) ----------
__global__ void k_conv(const float* __restrict__ in, unsigned short* __restrict__ out, int n8) {
    int t = blockIdx.x * blockDim.x + threadIdx.x;
    if (t >= n8) return;
    const float4* p = reinterpret_cast<const float4*>(in) + (size_t)t * 2;
    float4 a = p[0], b = p[1];
    u16x8 o;
    o[0] = f2bf(a.x); o[1] = f2bf(a.y); o[2] = f2bf(a.z); o[3] = f2bf(a.w);
    o[4] = f2bf(b.x); o[5] = f2bf(b.y); o[6] = f2bf(b.z); o[7] = f2bf(b.w);
    *(reinterpret_cast<u16x8*>(out) + t) = o;
}

// ---------- fp32 [R][C] -> bf16 [C][R] transpose-convert ----------
__global__ __launch_bounds__(256) void k_tconv(const float* __restrict__ in,
                                               unsigned short* __restrict__ out, int R, int C) {
    __shared__ float tile[64][65];
    int ct = C >> 6;
    int bx = blockIdx.x % ct;
    int by = blockIdx.x / ct;
    int r0 = by * 64, c0 = bx * 64;
    int tx = threadIdx.x & 63, ty = threadIdx.x >> 6;
#pragma unroll
    for (int rr = 0; rr < 16; rr++) {
        int row = ty + rr * 4;
        tile[row][tx] = in[(size_t)(r0 + row) * C + c0 + tx];
    }
    __syncthreads();
#pragma unroll
    for (int rr = 0; rr < 16; rr++) {
        int row = ty + rr * 4;
        out[(size_t)(c0 + row) * R + r0 + tx] = f2bf(tile[tx][row]);
    }
}

// ---------- QKV GEMM, 128x128 LDS tile: xb[8192][512] @ wbT^T -> q(scaled)/k/v ----------
__global__ __launch_bounds__(256) void k_qkv(const unsigned short* __restrict__ A,
                                             const unsigned short* __restrict__ BT,
                                             unsigned short* __restrict__ q,
                                             unsigned short* __restrict__ kk,
                                             unsigned short* __restrict__ vv) {
    __shared__ unsigned short Al[128 * 32];
    __shared__ unsigned short Bl[128 * 32];
    int mt = blockIdx.x / 12, nt = blockIdx.x % 12;
    int m0 = mt * 128, c0 = nt * 128;
    int tid = threadIdx.x, lane = tid & 63, w = tid >> 6;
    int wr = w >> 1, wc = w & 1;
    int lr = lane & 15, lb = lane >> 4;
    f32x4 acc[4][4] = {};
    const unsigned short* gA = A + (size_t)(m0 + 32 * w + (lane >> 2)) * DIMC + (lane & 3) * 8;
    const unsigned short* gB = BT + (size_t)(c0 + 32 * w + (lane >> 2)) * DIMC + (lane & 3) * 8;
    char* lA = (char*)Al + w * 2048;
    char* lB = (char*)Bl + w * 2048;
    for (int k0 = 0; k0 < DIMC; k0 += 32) {
        __syncthreads();
        GLOAD16(gA + k0, lA);
        GLOAD16(gA + k0 + 16 * DIMC, lA + 1024);
        GLOAD16(gB + k0, lB);
        GLOAD16(gB + k0 + 16 * DIMC, lB + 1024);
        __syncthreads();
        bf16x8 af[4], bfr[4];
#pragma unroll
        for (int mi = 0; mi < 4; mi++)
            af[mi] = *reinterpret_cast<const bf16x8*>(&Al[(64 * wr + 16 * mi + lr) * 32 + 8 * lb]);
#pragma unroll
        for (int ni = 0; ni < 4; ni++)
            bfr[ni] = *reinterpret_cast<const bf16x8*>(&Bl[(64 * wc + 16 * ni + lr) * 32 + 8 * lb]);
#pragma unroll
        for (int mi = 0; mi < 4; mi++)
#pragma unroll
            for (int ni = 0; ni < 4; ni++)
                acc[mi][ni] = MFMA(af[mi], bfr[ni], acc[mi][ni]);
    }
#pragma unroll
    for (int ni = 0; ni < 4; ni++) {
        int c = c0 + 64 * wc + 16 * ni + lr;
        int which = c >> 9, rem = c & 511, h = rem >> 6, d = rem & 63;
        unsigned short* dst = which == 0 ? q : (which == 1 ? kk : vv);
        float sc = which == 0 ? 0.125f : 1.0f;  // q pre-scaled by D^-0.5
#pragma unroll
        for (int mi = 0; mi < 4; mi++) {
#pragma unroll
            for (int r = 0; r < 4; r++) {
                int m = m0 + 64 * wr + 16 * mi + 4 * lb + r;
                int b = m >> 10, n = m & 1023;
                dst[(((size_t)(b * 8 + h) * 1024) + n) * 64 + d] = f2bf(acc[mi][ni][r] * sc);
            }
        }
    }
}

// ---------- v [bh][n][d] -> vT [bh][d][n] ----------
__global__ __launch_bounds__(256) void k_vtrans(const unsigned short* __restrict__ v,
                                                unsigned short* __restrict__ vT) {
    __shared__ unsigned short tile[64][72];
    int bh = blockIdx.x >> 4;
    int n0 = (blockIdx.x & 15) * 64;
    int t = threadIdx.x;
    int nl = t >> 2, c4 = t & 3;
    const u16x8* src = reinterpret_cast<const u16x8*>(v + ((size_t)bh * 1024 + n0 + nl) * 64 + c4 * 16);
    u16x8 x0 = src[0], x1 = src[1];
    *reinterpret_cast<u16x8*>(&tile[nl][c4 * 16]) = x0;
    *reinterpret_cast<u16x8*>(&tile[nl][c4 * 16 + 8]) = x1;
    __syncthreads();
    int dl = t >> 2, n4 = t & 3;
#pragma unroll
    for (int c = 0; c < 2; c++) {
        u16x8 o;
#pragma unroll
        for (int i = 0; i < 8; i++) o[i] = tile[n4 * 16 + 8 * c + i][dl];
        *reinterpret_cast<u16x8*>(vT + ((size_t)bh * 64 + dl) * 1024 + n0 + n4 * 16 + 8 * c) = o;
    }
}

// ---------- QK^T + full-row softmax -> P bf16 [bh][i][j] ----------
// block = (bh, 16 i-rows); grid 4096; 8 waves each own a 128-wide j strip.
// P stores repacked through per-wave LDS tile for 16B coalesced writes.
__global__ __launch_bounds__(512) void k_attn(const unsigned short* __restrict__ q,
                                              const unsigned short* __restrict__ kk,
                                              unsigned short* __restrict__ P) {
    __shared__ float redm[16][8];
    __shared__ float redl[16][8];
    __shared__ unsigned short stg[8][16 * 136];   // per-wave [16][136] (272B row stride)
    int blk = blockIdx.x;
    int bh = blk & 63, it = blk >> 6;
    int i0 = it * 16;
    int tid = threadIdx.x, w = tid >> 6, lane = tid & 63;
    int lr = lane & 15, lb = lane >> 4;
    int j0 = w * 128;
    const unsigned short* qp = q + (size_t)bh * 65536;
    const unsigned short* kp = kk + (size_t)bh * 65536;
    bf16x8 aq[2];
#pragma unroll
    for (int ks = 0; ks < 2; ks++)
        aq[ks] = *reinterpret_cast<const bf16x8*>(qp + (size_t)(i0 + lr) * 64 + 32 * ks + 8 * lb);
    f32x4 acc[8] = {};
#pragma unroll
    for (int nf = 0; nf < 8; nf++) {
#pragma unroll
        for (int ks = 0; ks < 2; ks++) {
            bf16x8 bk = *reinterpret_cast<const bf16x8*>(kp + (size_t)(j0 + 16 * nf + lr) * 64 + 32 * ks + 8 * lb);
            acc[nf] = MFMA(aq[ks], bk, acc[nf]);
        }
    }
    float mx[4], li[4];
#pragma unroll
    for (int r = 0; r < 4; r++) {
        float m = acc[0][r];
#pragma unroll
        for (int nf = 1; nf < 8; nf++) m = fmaxf(m, acc[nf][r]);
        m = fmaxf(m, __shfl_xor(m, 1)); m = fmaxf(m, __shfl_xor(m, 2));
        m = fmaxf(m, __shfl_xor(m, 4)); m = fmaxf(m, __shfl_xor(m, 8));
        mx[r] = m;
    }
    if (lr == 0) {
#pragma unroll
        for (int r = 0; r < 4; r++) redm[4 * lb + r][w] = mx[r];
    }
    __syncthreads();
#pragma unroll
    for (int r = 0; r < 4; r++) {
        float m = redm[4 * lb + r][0];
#pragma unroll
        for (int ww = 1; ww < 8; ww++) m = fmaxf(m, redm[4 * lb + r][ww]);
        mx[r] = m;
    }
#pragma unroll
    for (int r = 0; r < 4; r++) {
        float s = 0.f;
#pragma unroll
        for (int nf = 0; nf < 8; nf++) {
            float e = __expf(acc[nf][r] - mx[r]);
            acc[nf][r] = e;
            s += e;
        }
        s += __shfl_xor(s, 1); s += __shfl_xor(s, 2);
        s += __shfl_xor(s, 4); s += __shfl_xor(s, 8);
        li[r] = s;
    }
    if (lr == 0) {
#pragma unroll
        for (int r = 0; r < 4; r++) redl[4 * lb + r][w] = li[r];
    }
    __syncthreads();
#pragma unroll
    for (int r = 0; r < 4; r++) {
        float s = 0.f;
#pragma unroll
        for (int ww = 0; ww < 8; ww++) s += redl[4 * lb + r][ww];
        li[r] = 1.0f / s;
    }
    // stage normalized P into per-wave LDS tile, then coalesced 16B stores
    unsigned short* sp = &stg[w][0];
#pragma unroll
    for (int nf = 0; nf < 8; nf++)
#pragma unroll
        for (int r = 0; r < 4; r++)
            sp[(4 * lb + r) * 136 + 16 * nf + lr] = f2bf(acc[nf][r] * li[r]);
    unsigned short* pp = P + (size_t)bh * 1048576;
#pragma unroll
    for (int ss = 0; ss < 4; ss++) {
        int rowi = 4 * ss + lb;
        u16x8 vv = *reinterpret_cast<const u16x8*>(&stg[w][rowi * 136 + lr * 8]);
        *reinterpret_cast<u16x8*>(pp + (size_t)(i0 + rowi) * 1024 + j0 + lr * 8) = vv;
    }
}

// ---------- mix + LN + PV fused, async double-buffered P staging ----------
// block = (b, 16 i-rows); grid 512; 4 waves, wave w owns j in [w*256,(w+1)*256).
// Per 32-j chunk: ds_read chunk c's 8 head-slices from wave-private LDS buffer,
// issue global_load_lds prefetch of chunk c+1 (no barrier, no VGPR), mix+LN
// in-register (B-fragment-shaped), swapped-operand PV MFMA. vmcnt(0) gates the
// buffer swap. LDS dbuf (64 KB) reused as partial-O reduction scratch.
__global__ __launch_bounds__(256, 2) void k_mixpv(const unsigned short* __restrict__ P,
                                                  const unsigned short* __restrict__ vT,
                                                  const float* __restrict__ Wm,
                                                  const float* __restrict__ gamma,
                                                  const float* __restrict__ beta,
                                                  unsigned short* __restrict__ outh) {
    __shared__ unsigned short Pbuf[4][2][4096];  // per-wave dbuf 2x8KB; 64 KB total
    int blk = blockIdx.x;
    int b = blk & 7, it = blk >> 3;
    int i0 = it * 16;
    int tid = threadIdx.x, w = tid >> 6, lane = tid & 63;
    int li = lane & 15, hi = lane >> 4;
    float wv[64];
#pragma unroll
    for (int x2 = 0; x2 < 64; x2++) wv[x2] = Wm[x2];
    float cv[8];  // mean folding: c_h = sum_g W[h][g] / 8
#pragma unroll
    for (int h = 0; h < 8; h++) {
        float s = 0.f;
#pragma unroll
        for (int g = 0; g < 8; g++) s += wv[h * 8 + g];
        cv[h] = s * 0.125f;
    }
    float gv[8], bvv[8];
#pragma unroll
    for (int x2 = 0; x2 < 8; x2++) { gv[x2] = gamma[x2]; bvv[x2] = beta[x2]; }
    const unsigned short* pb = P + (size_t)b * 8388608 + (size_t)(i0 + li) * 1024 + 8 * hi + w * 256;
    const unsigned short* vb = vT + (size_t)b * 524288 + (size_t)li * 1024 + 8 * hi + w * 256;
    f32x4 accO[8][4] = {};
    // prologue: prefetch chunk 0 into buf 0
#pragma unroll
    for (int h = 0; h < 8; h++)
        GLOAD16(pb + (size_t)h * 1048576, (char*)&Pbuf[w][0][h * 512]);
#pragma unroll 1
    for (int c = 0; c < 8; c++) {
        int j0c = c * 32;
        int cur = c & 1;
        asm volatile("s_waitcnt vmcnt(0)" ::: "memory");
        u16x8 avh[8];
#pragma unroll
        for (int h = 0; h < 8; h++)
            avh[h] = *reinterpret_cast<const u16x8*>(&Pbuf[w][cur][h * 512 + lane * 8]);
        if (c < 7) {
#pragma unroll
            for (int h = 0; h < 8; h++)
                GLOAD16(pb + (size_t)h * 1048576 + j0c + 32, (char*)&Pbuf[w][cur ^ 1][h * 512]);
        }
        // mix + LN for 8 j-entries; results land as B-fragments per head g
        u16x8 bfrag[8];
#pragma unroll
        for (int jj = 0; jj < 8; jj++) {
            float a[8];
#pragma unroll
            for (int h = 0; h < 8; h++) a[h] = bf2f(avh[h][jj]);
            float mg[8];
#pragma unroll
            for (int g = 0; g < 8; g++) {
                float s = 0.f;
#pragma unroll
                for (int h = 0; h < 8; h++) s += a[h] * wv[h * 8 + g];
                mg[g] = s;
            }
            float mean = 0.f;
#pragma unroll
            for (int h = 0; h < 8; h++) mean += a[h] * cv[h];
            float vvar = 0.f;
#pragma unroll
            for (int g = 0; g < 8; g++) { float d = mg[g] - mean; vvar += d * d; }
            float rs = rsqrtf(vvar * 0.125f + 1e-5f);
#pragma unroll
            for (int g = 0; g < 8; g++)
                bfrag[g][jj] = f2bf((mg[g] - mean) * rs * gv[g] + bvv[g]);
        }
        // PV: O^T[d][i] += V^T[d][j] * PM^T[j][i] per head
#pragma unroll
        for (int g = 0; g < 8; g++) {
            const unsigned short* vg = vb + (size_t)g * 65536 + j0c;
            bf16x8 bf = *reinterpret_cast<const bf16x8*>(&bfrag[g]);
#pragma unroll
            for (int df = 0; df < 4; df++) {
                bf16x8 af = *reinterpret_cast<const bf16x8*>(vg + (size_t)df * 16384);
                accO[g][df] = MFMA(af, bf, accO[g][df]);
            }
        }
    }
    // epilogue: write this wave's partial O (accO[g][df][r] = O[i0+li][g*64+16df+4hi+r])
    // into its own 16 KB region of the (now dead) dbuf; 8B packed stores, XOR-swizzled.
    unsigned short* Opw = &Pbuf[w][0][0];
#pragma unroll
    for (int g = 0; g < 8; g++)
#pragma unroll
        for (int df = 0; df < 4; df++) {
            u16x4 pk;
#pragma unroll
            for (int r = 0; r < 4; r++) pk[r] = f2bf(accO[g][df][r]);
            int idx = li * 512 + g * 64 + df * 16 + hi * 4;
            int byteoff = (idx * 2) ^ ((li & 7) << 5);
            *reinterpret_cast<u16x4*>((char*)Opw + byteoff) = pk;
        }
    __syncthreads();
    // all threads: sum the 4 partials chunk-wise, store coalesced.
#pragma unroll
    for (int s = 0; s < 4; s++) {
        int kch = tid + s * 256;
        int row = kch >> 6, col = (kch & 63) * 8;
        int byteoff = ((row * 512 + col) * 2) ^ ((row & 7) << 5);
        float sum[8] = {};
#pragma unroll
        for (int pw = 0; pw < 4; pw++) {
            u16x8 pv = *reinterpret_cast<const u16x8*>((const char*)&Pbuf[pw][0][0] + byteoff);
#pragma unroll
            for (int e2 = 0; e2 < 8; e2++) sum[e2] += bf2f(pv[e2]);
        }
        u16x8 ov;
#pragma unroll
        for (int e2 = 0; e2 < 8; e2++) ov[e2] = f2bf(sum[e2]);
        *reinterpret_cast<u16x8*>(outh + (size_t)(b * 1024 + i0 + row) * 512 + col) = ov;
    }
}

// ---------- out = outh @ w_out + b_out (fp32 out), 128x128 LDS tile ----------
__global__ __launch_bounds__(256) void k_proj(const unsigned short* __restrict__ A,
                                              const unsigned short* __restrict__ BT,
                                              const float* __restrict__ bias,
                                              float* __restrict__ out) {
    __shared__ unsigned short Al[128 * 32];
    __shared__ unsigned short Bl[128 * 32];
    int mt = blockIdx.x >> 2, nt = blockIdx.x & 3;
    int m0 = mt * 128, c0 = nt * 128;
    int tid = threadIdx.x, lane = tid & 63, w = tid >> 6;
    int wr = w >> 1, wc = w & 1;
    int lr = lane & 15, lb = lane >> 4;
    f32x4 acc[4][4] = {};
    const unsigned short* gA = A + (size_t)(m0 + 32 * w + (lane >> 2)) * DIMC + (lane & 3) * 8;
    const unsigned short* gB = BT + (size_t)(c0 + 32 * w + (lane >> 2)) * DIMC + (lane & 3) * 8;
    char* lA = (char*)Al + w * 2048;
    char* lB = (char*)Bl + w * 2048;
    for (int k0 = 0; k0 < DIMC; k0 += 32) {
        __syncthreads();
        GLOAD16(gA + k0, lA);
        GLOAD16(gA + k0 + 16 * DIMC, lA + 1024);
        GLOAD16(gB + k0, lB);
        GLOAD16(gB + k0 + 16 * DIMC, lB + 1024);
        __syncthreads();
        bf16x8 af[4], bfr[4];
#pragma unroll
        for (int mi = 0; mi < 4; mi++)
            af[mi] = *reinterpret_cast<const bf16x8*>(&Al[(64 * wr + 16 * mi + lr) * 32 + 8 * lb]);
#pragma unroll
        for (int ni = 0; ni < 4; ni++)
            bfr[ni] = *reinterpret_cast<const bf16x8*>(&Bl[(64 * wc + 16 * ni + lr) * 32 + 8 * lb]);
#pragma unroll
        for (int mi = 0; mi < 4; mi++)
#pragma unroll
            for (int ni = 0; ni < 4; ni++)
                acc[mi][ni] = MFMA(af[mi], bfr[ni], acc[mi][ni]);
    }
#pragma unroll
    for (int ni = 0; ni < 4; ni++) {
        int c = c0 + 64 * wc + 16 * ni + lr;
        float bs = bias[c];
#pragma unroll
        for (int mi = 0; mi < 4; mi++) {
#pragma unroll
            for (int r = 0; r < 4; r++) {
                int m = m0 + 64 * wr + 16 * mi + 4 * lb + r;
                out[(size_t)m * 512 + c] = acc[mi][ni][r] + bs;
            }
        }
    }
}

extern "C" void kernel_launch(void* const* d_in, const int* in_sizes, int n_in,
                              void* d_out, int out_size, void* d_ws, size_t ws_size,
                              hipStream_t stream) {
    (void)in_sizes; (void)n_in; (void)out_size; (void)ws_size;
    const float* x      = (const float*)d_in[0];
    const float* w_qkv  = (const float*)d_in[1];
    const float* W      = (const float*)d_in[2];
    const float* gamma  = (const float*)d_in[3];
    const float* beta   = (const float*)d_in[4];
    const float* w_out  = (const float*)d_in[5];
    const float* b_out  = (const float*)d_in[6];
    float* out = (float*)d_out;

    char* ws = (char*)d_ws;
    unsigned short* xb   = (unsigned short*)(ws + 0);           //  8 MB  [8192][512]
    unsigned short* wbT  = (unsigned short*)(ws + 8388608);     //  1.5MB [1536][512]
    unsigned short* w_oT = (unsigned short*)(ws + 9961472);     //  0.5MB [512][512]
    unsigned short* q    = (unsigned short*)(ws + 10485760);    //  8 MB  [bh][n][d]
    unsigned short* k    = (unsigned short*)(ws + 18874368);    //  8 MB
    unsigned short* v    = (unsigned short*)(ws + 27262976);    //  8 MB
    unsigned short* vT   = (unsigned short*)(ws + 35651584);    //  8 MB  [bh][d][n]
    unsigned short* outh = (unsigned short*)(ws + 44040192);    //  8 MB  [8192][512]
    unsigned short* P    = (unsigned short*)(ws + 52428800);    // 128 MB [bh][i][j]

    k_conv<<<2048, 256, 0, stream>>>(x, xb, 8192 * 512 / 8);
    k_tconv<<<(512 / 64) * (1536 / 64), 256, 0, stream>>>(w_qkv, wbT, 512, 1536);
    k_tconv<<<(512 / 64) * (512 / 64), 256, 0, stream>>>(w_out, w_oT, 512, 512);
    k_qkv<<<(8192 / 128) * (1536 / 128), 256, 0, stream>>>(xb, wbT, q, k, v);
    k_vtrans<<<64 * 16, 256, 0, stream>>>(v, vT);
    k_attn<<<64 * 64, 512, 0, stream>>>(q, k, P);
    k_mixpv<<<8 * 64, 256, 0, stream>>>(P, vT, W, gamma, beta, outh);
    k_proj<<<(8192 / 128) * (512 / 128), 256, 0, stream>>>(outh, w_oT, b_out, out);
}